// Round 2
// baseline (264.034 us; speedup 1.0000x reference)
//
#include <hip/hip_runtime.h>
#include <math.h>

#define NELEC 10
#define NSPIN 2
#define NPER 5
#define DIM 3
#define NION 2
#define DP 32
#define NDENSE 64
#define NPERM 120
#define RS 324   // G row stride in floats: row*324 % 32 = row*4 -> the 5 rows land on
                 // disjoint bank groups {0-3}{4-7}{8-11}{12-15}{16-19}; 324*4 % 16 == 0 (float4 ok)

// tanh(x) = 1 - 2/(exp(2x)+1): branch-free, exact at +-1 saturation
// (exp->inf => 1-0; exp->0 => 1-2 = -1). ~2-3 ulp via native v_exp + IEEE div.
__device__ __forceinline__ float fast_tanh(float x) {
    float e = __expf(2.0f * x);
    return 1.0f - 2.0f / (e + 1.0f);
}

__device__ __forceinline__ unsigned pick_remove(unsigned& el, int d) {
    unsigned v = (el >> (4 * d)) & 0xFu;
    unsigned low = el & ((1u << (4 * d)) - 1u);
    el = low | ((el >> (4 * (d + 1))) << (4 * d));
    return v;
}

// ---------------- main: one block per (batch, spin), 2 waves ----------------
__global__ __launch_bounds__(128, 3) void antisym_kern(
    const float* __restrict__ elec_pos, const float* __restrict__ ion_pos,
    const float* __restrict__ bf_w, const float* __restrict__ bf_b,
    const float* __restrict__ w0, const float* __restrict__ b0,
    const float* __restrict__ w1, const float* __restrict__ b1,
    const float* __restrict__ w2, const float* __restrict__ b2,
    float* __restrict__ psum, int B)
{
    const int b = blockIdx.x;
    const int s = blockIdx.y;
    const int t = threadIdx.x;
    const int wave = t >> 6, lane = t & 63;

    __shared__ float s1e[NPER * DP];                    // 160 floats
    __shared__ __align__(16) float G[NPER][RS];         // 5 x 324 floats
    __shared__ double wpart[2];

    // ---- stage 1: stream_1e = tanh(feats @ bf_w + bf_b) for this spin's 5 electrons ----
    const float* ep = elec_pos + (b * NELEC + s * NPER) * DIM;
    const float i0x = ion_pos[0], i0y = ion_pos[1], i0z = ion_pos[2];
    const float i1x = ion_pos[3], i1y = ion_pos[4], i1z = ion_pos[5];
    for (int idx = t; idx < NPER * DP; idx += 128) {
        int j = idx >> 5, c = idx & 31;
        float ex = ep[j * 3 + 0], ey = ep[j * 3 + 1], ez = ep[j * 3 + 2];
        float dx0 = ex - i0x, dy0 = ey - i0y, dz0 = ez - i0z;
        float dx1 = ex - i1x, dy1 = ey - i1y, dz1 = ez - i1z;
        float n0 = sqrtf(dx0 * dx0 + dy0 * dy0 + dz0 * dz0);
        float n1 = sqrtf(dx1 * dx1 + dy1 * dy1 + dz1 * dz1);
        float acc = bf_b[c];
        acc += dx0 * bf_w[0 * DP + c];
        acc += dy0 * bf_w[1 * DP + c];
        acc += dz0 * bf_w[2 * DP + c];
        acc += dx1 * bf_w[3 * DP + c];
        acc += dy1 * bf_w[4 * DP + c];
        acc += dz1 * bf_w[5 * DP + c];
        acc += n0 * bf_w[6 * DP + c];
        acc += n1 * bf_w[7 * DP + c];
        s1e[idx] = fast_tanh(acc);
    }
    __syncthreads();

    // ---- stage 2: G[j][i][c] = s1e[j][:] @ w0[s][32i:32i+32, c] ----
    // wave 0: j = 0,2,4 ; wave 1: j = 1,3.  s1e row held in 8 float4 regs (broadcast).
    const float* w0s = w0 + s * (NPER * DP) * NDENSE;   // [160][64]
    for (int j = wave; j < NPER; j += 2) {
        float4 sv4[8];
        #pragma unroll
        for (int q = 0; q < 8; q++) sv4[q] = *(const float4*)(s1e + j * DP + q * 4);
        #pragma unroll
        for (int i = 0; i < NPER; i++) {
            float acc = 0.f;
            #pragma unroll
            for (int q = 0; q < 8; q++) {
                const float* wb = w0s + (i * DP + q * 4) * NDENSE + lane;  // coalesced
                acc += sv4[q].x * wb[0 * NDENSE];
                acc += sv4[q].y * wb[1 * NDENSE];
                acc += sv4[q].z * wb[2 * NDENSE];
                acc += sv4[q].w * wb[3 * NDENSE];
            }
            G[j][i * NDENSE + lane] = acc;
        }
    }
    __syncthreads();

    // ---- stage 3: one permutation per lane (2 waves x 60 perms) ----
    const int pid = wave * 60 + lane;
    float sign = 0.f;
    int p0 = 0, p1 = 0, p2 = 0, p3 = 0, p4 = 0;
    if (lane < 60) {
        int p = pid;
        unsigned el = 0x43210u;
        int d0 = p / 24; p -= d0 * 24;
        int d1 = p / 6;  p -= d1 * 6;
        int d2 = p / 2;  p -= d2 * 2;
        int d3 = p;
        p0 = pick_remove(el, d0);
        p1 = pick_remove(el, d1);
        p2 = pick_remove(el, d2);
        p3 = pick_remove(el, d3);
        p4 = el & 0xF;
        sign = ((d0 + d1 + d2 + d3) & 1) ? -1.f : 1.f;
    }

    const float* b0s = b0 + s * NDENSE;
    const float* w2s = w2 + s * NDENSE;     // w2 is [s][64][1]
    const float* g0 = &G[p0][0 * NDENSE];
    const float* g1 = &G[p1][1 * NDENSE];
    const float* g2 = &G[p2][2 * NDENSE];
    const float* g3 = &G[p3][3 * NDENSE];
    const float* g4 = &G[p4][4 * NDENSE];

    // h = tanh(sum of 5 G rows + b0); hdot = h @ w2 (hoisted residual term)
    float h[NDENSE];
    float hdot = 0.f;
    #pragma unroll
    for (int cc = 0; cc < NDENSE / 4; cc++) {
        float4 a = *(const float4*)(b0s + cc * 4);
        float4 q;
        q = *(const float4*)(g0 + cc * 4); a.x += q.x; a.y += q.y; a.z += q.z; a.w += q.w;
        q = *(const float4*)(g1 + cc * 4); a.x += q.x; a.y += q.y; a.z += q.z; a.w += q.w;
        q = *(const float4*)(g2 + cc * 4); a.x += q.x; a.y += q.y; a.z += q.z; a.w += q.w;
        q = *(const float4*)(g3 + cc * 4); a.x += q.x; a.y += q.y; a.z += q.z; a.w += q.w;
        q = *(const float4*)(g4 + cc * 4); a.x += q.x; a.y += q.y; a.z += q.z; a.w += q.w;
        float t0 = fast_tanh(a.x), t1 = fast_tanh(a.y), t2 = fast_tanh(a.z), t3 = fast_tanh(a.w);
        h[cc * 4 + 0] = t0; h[cc * 4 + 1] = t1; h[cc * 4 + 2] = t2; h[cc * 4 + 3] = t3;
        hdot += t0 * w2s[cc * 4 + 0] + t1 * w2s[cc * 4 + 1]
              + t2 * w2s[cc * 4 + 2] + t3 * w2s[cc * 4 + 3];
    }

    // out = sum_j tanh(h@w1[:,j] + b1[j]) * w2[j] + hdot + b2
    // k-outer, 32 accumulators, two half-passes: w1 row k is wave-uniform and
    // contiguous in the ORIGINAL [k][j] layout -> s_load, no transpose kernel.
    // k-loop fully unrolled so h[] keeps constant indices (stays in VGPRs).
    const float* w1s = w1 + s * NDENSE * NDENSE;
    const float* b1s = b1 + s * NDENSE;
    float outacc = 0.f;
    #pragma unroll 1
    for (int half = 0; half < 2; half++) {
        const int jo = half * 32;
        float v[32];
        #pragma unroll
        for (int j = 0; j < 32; j++) v[j] = b1s[jo + j];
        #pragma unroll
        for (int k = 0; k < NDENSE; k++) {
            const float hk = h[k];
            const float* row = w1s + k * NDENSE + jo;   // wave-uniform -> scalar loads
            #pragma unroll
            for (int j = 0; j < 32; j++) v[j] = fmaf(hk, row[j], v[j]);
        }
        #pragma unroll
        for (int j = 0; j < 32; j++) outacc += fast_tanh(v[j]) * w2s[jo + j];
    }
    float outv = outacc + hdot + b2[s];

    // signed perm sum in double (stay under the reference's own fp32 noise)
    double dv = (double)(sign * outv);
    #pragma unroll
    for (int off = 32; off > 0; off >>= 1) dv += __shfl_down(dv, off, 64);
    if (lane == 0) wpart[wave] = dv;
    __syncthreads();
    if (t == 0) psum[s * B + b] = (float)(wpart[0] + wpart[1]);
}

// ---------------- combine: log|ps0*ps1| + jastrow ----------------
__global__ void combine_kern(const float* __restrict__ psum,
                             const float* __restrict__ elec_pos,
                             const float* __restrict__ ion_pos,
                             const float* __restrict__ jk,
                             float* __restrict__ out, int B)
{
    int b = blockIdx.x * 256 + threadIdx.x;
    if (b >= B) return;
    const float i0x = ion_pos[0], i0y = ion_pos[1], i0z = ion_pos[2];
    const float i1x = ion_pos[3], i1y = ion_pos[4], i1z = ion_pos[5];
    const float j0 = jk[0], j1 = jk[1];
    const float* ep = elec_pos + b * NELEC * DIM;
    float jas = 0.f;
    #pragma unroll
    for (int e = 0; e < NELEC; e++) {
        float ex = ep[e * 3 + 0], ey = ep[e * 3 + 1], ez = ep[e * 3 + 2];
        float dx0 = ex - i0x, dy0 = ey - i0y, dz0 = ez - i0z;
        float dx1 = ex - i1x, dy1 = ey - i1y, dz1 = ez - i1z;
        jas += j0 * sqrtf(dx0 * dx0 + dy0 * dy0 + dz0 * dz0);
        jas += j1 * sqrtf(dx1 * dx1 + dy1 * dy1 + dz1 * dz1);
    }
    float ps0 = psum[b], ps1 = psum[B + b];
    out[b] = logf(fabsf(ps0 * ps1)) - jas;
}

extern "C" void kernel_launch(void* const* d_in, const int* in_sizes, int n_in,
                              void* d_out, int out_size, void* d_ws, size_t ws_size,
                              hipStream_t stream) {
    const float* elec_pos = (const float*)d_in[0];
    const float* ion_pos  = (const float*)d_in[1];
    const float* bf_w     = (const float*)d_in[2];
    const float* bf_b     = (const float*)d_in[3];
    const float* w0       = (const float*)d_in[4];
    const float* b0       = (const float*)d_in[5];
    const float* w1       = (const float*)d_in[6];
    const float* b1       = (const float*)d_in[7];
    const float* w2       = (const float*)d_in[8];
    const float* b2       = (const float*)d_in[9];
    const float* jk       = (const float*)d_in[10];
    float* out = (float*)d_out;

    const int B = in_sizes[0] / (NELEC * DIM);   // 2048

    float* psum = (float*)d_ws;                  // [2][B]

    hipLaunchKernelGGL(antisym_kern,
                       dim3(B, NSPIN), dim3(128), 0, stream,
                       elec_pos, ion_pos, bf_w, bf_b, w0, b0, w1, b1, w2, b2, psum, B);
    hipLaunchKernelGGL(combine_kern,
                       dim3((B + 255) / 256), dim3(256), 0, stream,
                       psum, elec_pos, ion_pos, jk, out, B);
}

// Round 5
// 204.061 us; speedup vs baseline: 1.2939x; 1.2939x over previous
//
#include <hip/hip_runtime.h>
#include <math.h>

#define NELEC 10
#define NSPIN 2
#define NPER 5
#define DIM 3
#define NION 2
#define DP 32
#define NDENSE 64
#define NPERM 120
#define RS 324   // G row stride (words): p*324 % 32 = 4p -> the 5 perm-rows hit disjoint
                 // bank quads {0-3}{4-7}{8-11}{12-15}{16-19}; 324*4 % 16 == 0 (b128 ok)

// tanh(x) = 1 - 2/(exp(2x)+1): branch-free, exact at +-1 saturation, ~2-3 ulp
__device__ __forceinline__ float fast_tanh(float x) {
    float e = __expf(2.0f * x);
    return 1.0f - 2.0f / (e + 1.0f);
}

__device__ __forceinline__ unsigned pick_remove(unsigned& el, int d) {
    unsigned v = (el >> (4 * d)) & 0xFu;
    unsigned low = el & ((1u << (4 * d)) - 1u);
    el = low | ((el >> (4 * (d + 1))) << (4 * d));
    return v;
}

// ---------------- main: one block per (batch, spin), 2 waves ----------------
// Structure identical to the round-2 validated kernel. ONLY change:
// __launch_bounds__(128, 1). R2's (128,3) mapped to 6 waves/EU -> VGPR cap 85
// (measured VGPR_Count=84) -> h[64]+v[32] spilled to scratch (WRITE_SIZE 7 MB).
// (128,1) -> cap 256 VGPRs -> the ~130-reg working set stays in registers.
__global__ __launch_bounds__(128, 1) void antisym_kern(
    const float* __restrict__ elec_pos, const float* __restrict__ ion_pos,
    const float* __restrict__ bf_w, const float* __restrict__ bf_b,
    const float* __restrict__ w0, const float* __restrict__ b0,
    const float* __restrict__ w1, const float* __restrict__ b1,
    const float* __restrict__ w2, const float* __restrict__ b2,
    float* __restrict__ psum, int B)
{
    const int b = blockIdx.x;
    const int s = blockIdx.y;
    const int t = threadIdx.x;
    const int wave = t >> 6, lane = t & 63;

    __shared__ float s1e[NPER * DP];                    // 160 floats
    __shared__ __align__(16) float G[NPER][RS];         // 5 x 324 floats
    __shared__ double wpart[2];

    // ---- stage 1: stream_1e = tanh(feats @ bf_w + bf_b) for this spin's 5 electrons ----
    const float* ep = elec_pos + (b * NELEC + s * NPER) * DIM;
    const float i0x = ion_pos[0], i0y = ion_pos[1], i0z = ion_pos[2];
    const float i1x = ion_pos[3], i1y = ion_pos[4], i1z = ion_pos[5];
    for (int idx = t; idx < NPER * DP; idx += 128) {
        int j = idx >> 5, c = idx & 31;
        float ex = ep[j * 3 + 0], ey = ep[j * 3 + 1], ez = ep[j * 3 + 2];
        float dx0 = ex - i0x, dy0 = ey - i0y, dz0 = ez - i0z;
        float dx1 = ex - i1x, dy1 = ey - i1y, dz1 = ez - i1z;
        float n0 = sqrtf(dx0 * dx0 + dy0 * dy0 + dz0 * dz0);
        float n1 = sqrtf(dx1 * dx1 + dy1 * dy1 + dz1 * dz1);
        float acc = bf_b[c];
        acc += dx0 * bf_w[0 * DP + c];
        acc += dy0 * bf_w[1 * DP + c];
        acc += dz0 * bf_w[2 * DP + c];
        acc += dx1 * bf_w[3 * DP + c];
        acc += dy1 * bf_w[4 * DP + c];
        acc += dz1 * bf_w[5 * DP + c];
        acc += n0 * bf_w[6 * DP + c];
        acc += n1 * bf_w[7 * DP + c];
        s1e[idx] = fast_tanh(acc);
    }
    __syncthreads();

    // ---- stage 2: G[j][i*64+c] = s1e[j][:] @ w0[s][32i:32i+32, c] ----
    // wave 0: j = 0,2,4 ; wave 1: j = 1,3.  s1e row held in 8 float4 regs (broadcast).
    const float* w0s = w0 + s * (NPER * DP) * NDENSE;   // [160][64]
    for (int j = wave; j < NPER; j += 2) {
        float4 sv4[8];
        #pragma unroll
        for (int q = 0; q < 8; q++) sv4[q] = *(const float4*)(s1e + j * DP + q * 4);
        #pragma unroll
        for (int i = 0; i < NPER; i++) {
            float acc = 0.f;
            #pragma unroll
            for (int q = 0; q < 8; q++) {
                const float* wb = w0s + (i * DP + q * 4) * NDENSE + lane;  // coalesced
                acc += sv4[q].x * wb[0 * NDENSE];
                acc += sv4[q].y * wb[1 * NDENSE];
                acc += sv4[q].z * wb[2 * NDENSE];
                acc += sv4[q].w * wb[3 * NDENSE];
            }
            G[j][i * NDENSE + lane] = acc;
        }
    }
    __syncthreads();

    // ---- stage 3: one permutation per lane (2 waves x 60 perms) ----
    const int pid = wave * 60 + lane;
    float sign = 0.f;
    int p0 = 0, p1 = 0, p2 = 0, p3 = 0, p4 = 0;
    if (lane < 60) {
        int p = pid;
        unsigned el = 0x43210u;
        int d0 = p / 24; p -= d0 * 24;
        int d1 = p / 6;  p -= d1 * 6;
        int d2 = p / 2;  p -= d2 * 2;
        int d3 = p;
        p0 = pick_remove(el, d0);
        p1 = pick_remove(el, d1);
        p2 = pick_remove(el, d2);
        p3 = pick_remove(el, d3);
        p4 = el & 0xF;
        sign = ((d0 + d1 + d2 + d3) & 1) ? -1.f : 1.f;
    }

    const float* b0s = b0 + s * NDENSE;
    const float* w2s = w2 + s * NDENSE;     // w2 is [s][64][1]
    const float* g0 = &G[p0][0 * NDENSE];
    const float* g1 = &G[p1][1 * NDENSE];
    const float* g2 = &G[p2][2 * NDENSE];
    const float* g3 = &G[p3][3 * NDENSE];
    const float* g4 = &G[p4][4 * NDENSE];

    // h = tanh(sum of 5 G rows + b0); hdot = h @ w2 (hoisted residual term)
    float h[NDENSE];
    float hdot = 0.f;
    #pragma unroll
    for (int cc = 0; cc < NDENSE / 4; cc++) {
        float4 a = *(const float4*)(b0s + cc * 4);
        float4 q;
        q = *(const float4*)(g0 + cc * 4); a.x += q.x; a.y += q.y; a.z += q.z; a.w += q.w;
        q = *(const float4*)(g1 + cc * 4); a.x += q.x; a.y += q.y; a.z += q.z; a.w += q.w;
        q = *(const float4*)(g2 + cc * 4); a.x += q.x; a.y += q.y; a.z += q.z; a.w += q.w;
        q = *(const float4*)(g3 + cc * 4); a.x += q.x; a.y += q.y; a.z += q.z; a.w += q.w;
        q = *(const float4*)(g4 + cc * 4); a.x += q.x; a.y += q.y; a.z += q.z; a.w += q.w;
        float t0 = fast_tanh(a.x), t1 = fast_tanh(a.y), t2 = fast_tanh(a.z), t3 = fast_tanh(a.w);
        h[cc * 4 + 0] = t0; h[cc * 4 + 1] = t1; h[cc * 4 + 2] = t2; h[cc * 4 + 3] = t3;
        hdot += t0 * w2s[cc * 4 + 0] + t1 * w2s[cc * 4 + 1]
              + t2 * w2s[cc * 4 + 2] + t3 * w2s[cc * 4 + 3];
    }

    // out = sum_j tanh(h@w1[:,j] + b1[j]) * w2[j] + hdot + b2
    // k-outer, 32 accumulators, two half-passes: w1 row k is wave-uniform and
    // contiguous in the ORIGINAL [k][j] layout -> s_load, no transpose kernel.
    const float* w1s = w1 + s * NDENSE * NDENSE;
    const float* b1s = b1 + s * NDENSE;
    float outacc = 0.f;
    #pragma unroll 1
    for (int half = 0; half < 2; half++) {
        const int jo = half * 32;
        float v[32];
        #pragma unroll
        for (int j = 0; j < 32; j++) v[j] = b1s[jo + j];
        #pragma unroll
        for (int k = 0; k < NDENSE; k++) {
            const float hk = h[k];
            const float* row = w1s + k * NDENSE + jo;   // wave-uniform -> scalar loads
            #pragma unroll
            for (int j = 0; j < 32; j++) v[j] = fmaf(hk, row[j], v[j]);
        }
        #pragma unroll
        for (int j = 0; j < 32; j++) outacc += fast_tanh(v[j]) * w2s[jo + j];
    }
    float outv = outacc + hdot + b2[s];

    // signed perm sum in double (stay under the reference's own fp32 noise)
    double dv = (double)(sign * outv);
    #pragma unroll
    for (int off = 32; off > 0; off >>= 1) dv += __shfl_down(dv, off, 64);
    if (lane == 0) wpart[wave] = dv;
    __syncthreads();
    if (t == 0) psum[s * B + b] = (float)(wpart[0] + wpart[1]);
}

// ---------------- combine: log|ps0*ps1| + jastrow (validated R1/R2 form) ----------------
__global__ void combine_kern(const float* __restrict__ psum,
                             const float* __restrict__ elec_pos,
                             const float* __restrict__ ion_pos,
                             const float* __restrict__ jk,
                             float* __restrict__ out, int B)
{
    int b = blockIdx.x * 256 + threadIdx.x;
    if (b >= B) return;
    const float i0x = ion_pos[0], i0y = ion_pos[1], i0z = ion_pos[2];
    const float i1x = ion_pos[3], i1y = ion_pos[4], i1z = ion_pos[5];
    const float j0 = jk[0], j1 = jk[1];
    const float* ep = elec_pos + b * NELEC * DIM;
    float jas = 0.f;
    #pragma unroll
    for (int e = 0; e < NELEC; e++) {
        float ex = ep[e * 3 + 0], ey = ep[e * 3 + 1], ez = ep[e * 3 + 2];
        float dx0 = ex - i0x, dy0 = ey - i0y, dz0 = ez - i0z;
        float dx1 = ex - i1x, dy1 = ey - i1y, dz1 = ez - i1z;
        jas += j0 * sqrtf(dx0 * dx0 + dy0 * dy0 + dz0 * dz0);
        jas += j1 * sqrtf(dx1 * dx1 + dy1 * dy1 + dz1 * dz1);
    }
    float ps0 = psum[b], ps1 = psum[B + b];
    out[b] = logf(fabsf(ps0 * ps1)) - jas;
}

extern "C" void kernel_launch(void* const* d_in, const int* in_sizes, int n_in,
                              void* d_out, int out_size, void* d_ws, size_t ws_size,
                              hipStream_t stream) {
    const float* elec_pos = (const float*)d_in[0];
    const float* ion_pos  = (const float*)d_in[1];
    const float* bf_w     = (const float*)d_in[2];
    const float* bf_b     = (const float*)d_in[3];
    const float* w0       = (const float*)d_in[4];
    const float* b0       = (const float*)d_in[5];
    const float* w1       = (const float*)d_in[6];
    const float* b1       = (const float*)d_in[7];
    const float* w2       = (const float*)d_in[8];
    const float* b2       = (const float*)d_in[9];
    const float* jk       = (const float*)d_in[10];
    float* out = (float*)d_out;

    const int B = in_sizes[0] / (NELEC * DIM);   // 2048

    float* psum = (float*)d_ws;                  // [2][B]

    hipLaunchKernelGGL(antisym_kern,
                       dim3(B, NSPIN), dim3(128), 0, stream,
                       elec_pos, ion_pos, bf_w, bf_b, w0, b0, w1, b1, w2, b2, psum, B);
    hipLaunchKernelGGL(combine_kern,
                       dim3((B + 255) / 256), dim3(256), 0, stream,
                       psum, elec_pos, ion_pos, jk, out, B);
}